// Round 9
// baseline (231.863 us; speedup 1.0000x reference)
//
#include <hip/hip_runtime.h>
#include <hip/hip_bf16.h>
#include <math.h>

// Problem constants
#define B_  8
#define N_  32
#define M_  16
#define LX  32
#define D_  64
#define IN_DIM_ 17
#define TT_ 63
#define H_  4
#define DH_ 16
#define P_TOT 4096          // B*N*M
#define BN_ 256             // B*N
#define FF_ 2048

// Fragment pool layout (slot = one short8/uint4 per lane-group entry)
#define FRAG_TOT 83200
#define OFF_INW  2048
#define OFF_OUTW 3584
#define OFF_FW1  4096
#define OFF_FW2  20480

typedef unsigned short ushort_t;
typedef __attribute__((ext_vector_type(8))) short short8;   // 8 bf16 (4 VGPRs)
typedef __attribute__((ext_vector_type(4))) float floatx4;  // MFMA C/D

#define MFMA16(a,b,c) __builtin_amdgcn_mfma_f32_16x16x32_bf16((a),(b),(c),0,0,0)

__device__ __forceinline__ float fast_exp2(float x){
#if __has_builtin(__builtin_amdgcn_exp2f)
  return __builtin_amdgcn_exp2f(x);
#else
  return __expf(x * 0.6931471805599453f);
#endif
}
__device__ __forceinline__ float fast_rcp(float x){
#if __has_builtin(__builtin_amdgcn_rcpf)
  return __builtin_amdgcn_rcpf(x);
#else
  return 1.0f / x;
#endif
}

__device__ __forceinline__ ushort_t f2bf(float f){          // RNE float->bf16
  unsigned u = __float_as_uint(f);
  u += 0x7FFFu + ((u >> 16) & 1u);
  return (ushort_t)(u >> 16);
}
__device__ __forceinline__ float bf2f(ushort_t h){ return __uint_as_float(((unsigned)h) << 16); }

__device__ __forceinline__ uint4 pack8(const ushort_t* h){
  uint4 u;
  u.x = (unsigned)h[0] | ((unsigned)h[1] << 16);
  u.y = (unsigned)h[2] | ((unsigned)h[3] << 16);
  u.z = (unsigned)h[4] | ((unsigned)h[5] << 16);
  u.w = (unsigned)h[6] | ((unsigned)h[7] << 16);
  return u;
}

// split 8 consecutive floats into hi/lo bf16 short8
__device__ __forceinline__ void split8(const float* r, short8& hi, short8& lo){
  #pragma unroll
  for (int j = 0; j < 8; ++j){
    float v = r[j];
    ushort_t h = f2bf(v);
    ushort_t l2 = f2bf(v - bf2f(h));
    hi[j] = (short)h; lo[j] = (short)l2;
  }
}
// hi-only conversion -> uint4
__device__ __forceinline__ uint4 cvt8(const float* r){
  ushort_t hh[8];
  #pragma unroll
  for (int j = 0; j < 8; ++j) hh[j] = f2bf(r[j]);
  return pack8(hh);
}
// hi-only conversion -> short8
__device__ __forceinline__ short8 cvt8s(const float* r){
  union { uint4 u4; short8 s8; } cv;
  cv.u4 = cvt8(r);
  return cv.s8;
}

// 3-term split product: (ah+al)(bh+bl) ~= ah*bh + ah*bl + al*bh
__device__ __forceinline__ floatx4 mm3(short8 ah, short8 al, short8 bh, short8 bl, floatx4 c){
  c = MFMA16(ah, bh, c); c = MFMA16(ah, bl, c); c = MFMA16(al, bh, c); return c;
}

__device__ __forceinline__ float dot64(const float* __restrict__ a, const float* __restrict__ w){
  const float4* a4 = (const float4*)a;
  const float4* w4 = (const float4*)w;
  float acc = 0.f;
  #pragma unroll
  for (int k = 0; k < 16; ++k){ float4 x = a4[k], y = w4[k];
    acc += x.x*y.x + x.y*y.y + x.z*y.z + x.w*y.w; }
  return acc;
}
__device__ __forceinline__ float dot16(const float* __restrict__ a, const float* __restrict__ b){
  const float4* a4 = (const float4*)a; const float4* b4 = (const float4*)b;
  float acc = 0.f;
  #pragma unroll
  for (int k = 0; k < 4; ++k){ float4 x = a4[k], y = b4[k];
    acc += x.x*y.x + x.y*y.y + x.z*y.z + x.w*y.w; }
  return acc;
}

// pack A-frags (16 tokens x 64 k) from stride-68 LDS buffer into fragA (hi[128], lo[128])
__device__ __forceinline__ void packA68(const float* buf, short8* fA, int tid){
  if (tid < 128){
    int ln = tid & 63, ks = tid >> 6;
    const float* r = buf + (ln & 15)*68 + ks*32 + ((ln >> 4) & 3)*8;
    short8 hi, lo; split8(r, hi, lo);
    fA[tid] = hi; fA[128 + tid] = lo;
  }
}

// in-wave 64-lane sum reduction (6 shfl)
__device__ __forceinline__ float wsum64(float v){
  v += __shfl_xor(v, 1, 64);  v += __shfl_xor(v, 2, 64);
  v += __shfl_xor(v, 4, 64);  v += __shfl_xor(v, 8, 64);
  v += __shfl_xor(v, 16, 64); v += __shfl_xor(v, 32, 64);
  return v;
}

// -------------------------------------------------------------------------
// Prep: convert ALL weight matrices to MFMA B-fragment pool (hi at [s], lo at
// [FRAG_TOT+s]; lo only written for attn segments — ttcn + FF consume hi only).
// B[k][n]: n = nt*16 + (lane&15), k = ks*32 + quad*8 + j.
// w3 special: (a) columns reordered so tile nt covers i = nt>>2 (constant per
// tile), t = (nt&3)*16 + lane&15; (b) k=63 slot = 1.0 (mask carrier);
// (c) ALL w3 values scaled by log2(e) so epilogue uses raw v_exp_f32.
// -------------------------------------------------------------------------
__global__ __launch_bounds__(256) void prep_kernel(
    const float* __restrict__ w1, const float* __restrict__ w2, const float* __restrict__ w3,
    const float* __restrict__ gqw, const float* __restrict__ gkw,
    const float* __restrict__ gvw, const float* __restrict__ gow,
    const float* __restrict__ inw, const float* __restrict__ outw,
    const float* __restrict__ fw1, const float* __restrict__ fw2,
    uint4* __restrict__ fr)
{
  int s = blockIdx.x*256 + threadIdx.x;
  if (s >= FRAG_TOT) return;
  const float* src; int Nr, Kr, KS, rel; int w3seg = 0, noLo = 0;
  if (s < 256)      { src = w1; Nr=63;  Kr=17; KS=1; rel = s; noLo = 1; }
  else if (s < 768) { src = w2; Nr=63;  Kr=63; KS=2; rel = s-256; noLo = 1; }
  else if (s < 9472){ src = w3; Nr=1071;Kr=63; KS=2; rel = s-768; w3seg = 1; noLo = 1; }
  else {
    int t = s - 9472, l = t / 36864, r2 = t - l*36864;
    if (r2 < 512)        { src = gqw + l*4096;   Nr=64;  Kr=64;   KS=2;  rel = r2; }
    else if (r2 < 1024)  { src = gkw + l*4096;   Nr=64;  Kr=64;   KS=2;  rel = r2-512; }
    else if (r2 < 1536)  { src = gvw + l*4096;   Nr=64;  Kr=64;   KS=2;  rel = r2-1024; }
    else if (r2 < 2048)  { src = gow + l*4096;   Nr=64;  Kr=64;   KS=2;  rel = r2-1536; }
    else if (r2 < 3584)  { src = inw + l*12288;  Nr=192; Kr=64;   KS=2;  rel = r2-2048; }
    else if (r2 < 4096)  { src = outw + l*4096;  Nr=64;  Kr=64;   KS=2;  rel = r2-3584; }
    else if (r2 < 20480) { src = fw1 + l*131072; Nr=2048;Kr=64;   KS=2;  rel = r2-4096; noLo = 1; }
    else                 { src = fw2 + l*131072; Nr=64;  Kr=2048; KS=64; rel = r2-20480; noLo = 1; }
  }
  int lane = rel & 63, tmp = rel >> 6;
  int ks = tmp % KS, nt = tmp / KS;
  int kb = ks*32 + ((lane >> 4) & 3)*8;
  int n, validn;
  if (w3seg){
    int i = nt >> 2, tq = nt & 3;
    int t = tq*16 + (lane & 15);
    n = t*17 + i;                         // source row of w3 (c = t*17+i)
    validn = (t < 63);
  } else {
    n = nt*16 + (lane & 15);
    validn = (n < Nr);
  }
  float v[8];
  #pragma unroll
  for (int j = 0; j < 8; ++j){
    v[j] = (validn && (kb + j) < Kr) ? src[n*Kr + kb + j] : 0.f;
    if (w3seg){
      if ((kb + j) == 63) v[j] = 1.0f;               // mask-carrier column
      v[j] *= 1.4426950408889634f;                   // log2(e) for exp2 epilogue
    }
  }
  ushort_t hh[8];
  #pragma unroll
  for (int j = 0; j < 8; ++j) hh[j] = f2bf(v[j]);
  fr[s] = pack8(hh);
  if (!noLo){
    ushort_t ll[8];
    #pragma unroll
    for (int j = 0; j < 8; ++j) ll[j] = f2bf(v[j] - bf2f(hh[j]));
    fr[FRAG_TOT + s] = pack8(ll);
  }
}

// -------------------------------------------------------------------------
// Fused TTCN — R9: TWO patches per block (p, p+2048), grid 2048. All phases
// run both patches with SHARED weight B-fragments; P6 interleaves two
// independent MFMA->exp->shfl->rcp chains per iteration (2x ILP per wave).
// Per-patch valid-row compaction retained (block-uniform two0/two1).
// Plain R4-style loop bodies (no lambdas / hand prefetch — proven safe).
// -------------------------------------------------------------------------
__global__ __launch_bounds__(256) void ttcn_kernel(
    const float* __restrict__ x, const int* __restrict__ mask,
    const float* __restrict__ b1, const float* __restrict__ b2,
    const float* __restrict__ tb,
    const short8* __restrict__ w1bhi,
    const short8* __restrict__ w2bhi,
    const short8* __restrict__ w3bhi,
    float* __restrict__ xp, float* __restrict__ pm,
    float* __restrict__ xsws)
{
  __shared__ __align__(16) char pool[33024];
  float*    xs0   = (float*)(pool + 0);        // 32x20 f
  float*    xs1   = (float*)(pool + 2560);
  float*    xst0  = (float*)(pool + 5120);     // 17x36 f
  float*    xst1  = (float*)(pool + 7568);
  int*      cmap0 = (int*)  (pool + 10016);    // 32 ints
  int*      cmap1 = (int*)  (pool + 10144);
  float*    xsum0 = (float*)(pool + 10272);    // 17 f
  float*    xsum1 = (float*)(pool + 10344);
  int*      Vp0   = (int*)  (pool + 10416);
  int*      Vp1   = (int*)  (pool + 10420);
  short8*   xfhi0 = (short8*)(pool + 10432);   // 128 slots
  short8*   xfhi1 = (short8*)(pool + 12480);
  ushort_t* h1t0  = (ushort_t*)(pool + 14528); // 32x72 bf16
  ushort_t* h1t1  = (ushort_t*)(pool + 19136);
  ushort_t* h2t0  = (ushort_t*)(pool + 23744);
  ushort_t* h2t1  = (ushort_t*)(pool + 28352);

  const int p0 = blockIdx.x, p1 = blockIdx.x + 2048, tid = threadIdx.x;
  const int lane = tid & 63, wvi = tid >> 6;
  const int nidx = lane & 15, quad = lane >> 4;

  // zero the atomic-mean accumulator (128 blocks x 64 floats)
  if (p0 < 128 && tid < 64) xsws[p0*64 + tid] = 0.f;

  // P0: stage both patches (stride 20) + per-patch ballot (waves 0,1)
  for (int idx = tid; idx < LX*IN_DIM_; idx += 256){
    int l = (idx * 3856) >> 16;             // idx/17 exact for idx<1088
    int i = idx - l*17;
    xs0[l*20 + i] = x[p0*(LX*IN_DIM_) + idx];
  }
  for (int idx = tid; idx < LX*IN_DIM_; idx += 256){
    int l = (idx * 3856) >> 16;
    int i = idx - l*17;
    xs1[l*20 + i] = x[p1*(LX*IN_DIM_) + idx];
  }
  if (tid < 128){
    int wv = tid >> 6, ln = tid & 63;
    int pp = wv ? p1 : p0;
    int* cm = wv ? cmap1 : cmap0;
    int* VP = wv ? Vp1 : Vp0;
    int mv = (ln < 32) ? mask[pp*LX + ln] : 0;
    unsigned long long bal = __ballot(mv != 0);
    if (ln < 32) cm[ln] = 0;
    int pos = __popcll(bal & ((1ull << ln) - 1ull));
    if (mv != 0) cm[pos] = ln;
    if (ln == 0) *VP = (int)__popcll(bal);
  }
  __syncthreads();
  const int V0 = *Vp0, V1 = *Vp1;
  const int two0 = (V0 > 16), two1 = (V1 > 16);

  // P1: A-fragments (256 threads: tid>>7 selects patch), xsum, compacted xst
  {
    int pp = tid >> 7;
    int mt = (tid >> 6) & 1;
    const int* cm = pp ? cmap1 : cmap0;
    int twoX = pp ? two1 : two0;
    const float* xsX = pp ? xs1 : xs0;
    short8* xf = pp ? xfhi1 : xfhi0;
    if (mt == 0 || twoX){
      int lc = cm[mt*16 + nidx];
      float r[8];
      #pragma unroll
      for (int j = 0; j < 8; ++j){
        int k = quad*8 + j;
        r[j] = (k < IN_DIM_) ? xsX[lc*20 + k] : 0.f;
      }
      ((uint4*)xf)[tid & 127] = cvt8(r);
    }
  }
  if (tid < IN_DIM_){
    float s = 0.f;
    #pragma unroll
    for (int l = 0; l < LX; ++l) s += xs0[l*20 + tid];
    xsum0[tid] = s;
  } else if (tid >= 128 && tid < 128 + IN_DIM_){
    int i = tid - 128;
    float s = 0.f;
    #pragma unroll
    for (int l = 0; l < LX; ++l) s += xs1[l*20 + i];
    xsum1[i] = s;
  }
  if (two0){
    for (int idx = tid; idx < 544; idx += 256){
      int i = idx >> 5, cl = idx & 31;
      xst0[i*36 + cl] = xs0[cmap0[cl]*20 + i];
    }
  } else {
    for (int idx = tid; idx < 272; idx += 256){
      int i = idx >> 4, cl = idx & 15;
      xst0[i*36 + cl] = xs0[cmap0[cl]*20 + i];
    }
  }
  if (two1){
    for (int idx = tid; idx < 544; idx += 256){
      int i = idx >> 5, cl = idx & 31;
      xst1[i*36 + cl] = xs1[cmap1[cl]*20 + i];
    }
  } else {
    for (int idx = tid; idx < 272; idx += 256){
      int i = idx >> 4, cl = idx & 15;
      xst1[i*36 + cl] = xs1[cmap1[cl]*20 + i];
    }
  }
  __syncthreads();

  // P2: GEMM1 both patches, shared bh
  {
    int t = wvi*16 + nidx;
    float bb = (t < TT_) ? b1[t] : 0.f;
    short8 bh = w1bhi[wvi*64 + lane];
    {
      short8 axh0 = xfhi0[lane];
      floatx4 a0 = {0.f,0.f,0.f,0.f};
      a0 = MFMA16(axh0, bh, a0);
      if (two0){
        short8 axh1 = xfhi0[64 + lane];
        floatx4 a1 = {0.f,0.f,0.f,0.f};
        a1 = MFMA16(axh1, bh, a1);
        #pragma unroll
        for (int r = 0; r < 4; ++r)
          h1t0[(16+quad*4+r)*72 + t] = f2bf(fmaxf(a1[r] + bb, 0.f));
      }
      #pragma unroll
      for (int r = 0; r < 4; ++r)
        h1t0[(quad*4+r)*72 + t] = f2bf(fmaxf(a0[r] + bb, 0.f));
    }
    {
      short8 axh0 = xfhi1[lane];
      floatx4 a0 = {0.f,0.f,0.f,0.f};
      a0 = MFMA16(axh0, bh, a0);
      if (two1){
        short8 axh1 = xfhi1[64 + lane];
        floatx4 a1 = {0.f,0.f,0.f,0.f};
        a1 = MFMA16(axh1, bh, a1);
        #pragma unroll
        for (int r = 0; r < 4; ++r)
          h1t1[(16+quad*4+r)*72 + t] = f2bf(fmaxf(a1[r] + bb, 0.f));
      }
      #pragma unroll
      for (int r = 0; r < 4; ++r)
        h1t1[(quad*4+r)*72 + t] = f2bf(fmaxf(a0[r] + bb, 0.f));
    }
  }
  __syncthreads();

  // P4: GEMM2 both patches, shared bh0/bh1
  {
    int t = wvi*16 + nidx;
    float bb = (t < TT_) ? b2[t] : 0.f;
    short8 bh0 = w2bhi[(wvi*2+0)*64 + lane];
    short8 bh1 = w2bhi[(wvi*2+1)*64 + lane];
    {
      short8 a00 = *(const short8*)((const char*)h1t0 + (nidx*72 + quad*8)*2);
      short8 a01 = *(const short8*)((const char*)h1t0 + (nidx*72 + 32 + quad*8)*2);
      floatx4 a0 = {0.f,0.f,0.f,0.f};
      a0 = MFMA16(a00, bh0, a0); a0 = MFMA16(a01, bh1, a0);
      if (two0){
        short8 a10 = *(const short8*)((const char*)h1t0 + ((16+nidx)*72 + quad*8)*2);
        short8 a11 = *(const short8*)((const char*)h1t0 + ((16+nidx)*72 + 32 + quad*8)*2);
        floatx4 a1 = {0.f,0.f,0.f,0.f};
        a1 = MFMA16(a10, bh0, a1); a1 = MFMA16(a11, bh1, a1);
        #pragma unroll
        for (int r = 0; r < 4; ++r)
          h2t0[(16+quad*4+r)*72 + t] = f2bf(fmaxf(a1[r] + bb, 0.f));
      }
      #pragma unroll
      for (int r = 0; r < 4; ++r)
        h2t0[(quad*4+r)*72 + t] = f2bf(fmaxf(a0[r] + bb, 0.f));
    }
    {
      short8 a00 = *(const short8*)((const char*)h1t1 + (nidx*72 + quad*8)*2);
      short8 a01 = *(const short8*)((const char*)h1t1 + (nidx*72 + 32 + quad*8)*2);
      floatx4 a0 = {0.f,0.f,0.f,0.f};
      a0 = MFMA16(a00, bh0, a0); a0 = MFMA16(a01, bh1, a0);
      if (two1){
        short8 a10 = *(const short8*)((const char*)h1t1 + ((16+nidx)*72 + quad*8)*2);
        short8 a11 = *(const short8*)((const char*)h1t1 + ((16+nidx)*72 + 32 + quad*8)*2);
        floatx4 a1 = {0.f,0.f,0.f,0.f};
        a1 = MFMA16(a10, bh0, a1); a1 = MFMA16(a11, bh1, a1);
        #pragma unroll
        for (int r = 0; r < 4; ++r)
          h2t1[(16+quad*4+r)*72 + t] = f2bf(fmaxf(a1[r] + bb, 0.f));
      }
      #pragma unroll
      for (int r = 0; r < 4; ++r)
        h2t1[(quad*4+r)*72 + t] = f2bf(fmaxf(a0[r] + bb, 0.f));
    }
  }
  __syncthreads();

  // P6: GEMM3 + softmax + contract, both patches interleaved per iteration.
  {
    short8 ahA[2], ahB[2], ahC[2], ahD[2];
    #pragma unroll
    for (int ks = 0; ks < 2; ++ks){
      ahA[ks] = *(const short8*)((const char*)h2t0 + (nidx*72 + ks*32 + quad*8)*2);
      ahC[ks] = *(const short8*)((const char*)h2t1 + (nidx*72 + ks*32 + quad*8)*2);
    }
    if (two0){
      #pragma unroll
      for (int ks = 0; ks < 2; ++ks)
        ahB[ks] = *(const short8*)((const char*)h2t0 + ((16+nidx)*72 + ks*32 + quad*8)*2);
    }
    if (two1){
      #pragma unroll
      for (int ks = 0; ks < 2; ++ks)
        ahD[ks] = *(const short8*)((const char*)h2t1 + ((16+nidx)*72 + ks*32 + quad*8)*2);
    }
    // carriers
    if (quad == 3){
      if (two0) ahB[1][7] = (short)((16 + nidx >= V0) ? f2bf(-1e8f) : (ushort_t)0);
      else      ahA[1][7] = (short)((nidx >= V0)      ? f2bf(-1e8f) : (ushort_t)0);
      if (two1) ahD[1][7] = (short)((16 + nidx >= V1) ? f2bf(-1e8f) : (ushort_t)0);
      else      ahC[1][7] = (short)((nidx >= V1)      ? f2bf(-1e8f) : (ushort_t)0);
    }
    const int t_out = wvi*16 + nidx;
    const int rA = quad*4;
    float accA = 0.f, accB = 0.f;
    short8 nbh0 = w3bhi[(wvi*2+0)*64 + lane];
    short8 nbh1 = w3bhi[(wvi*2+1)*64 + lane];
    for (int it = 0; it < 17; ++it){
      short8 bh0 = nbh0, bh1 = nbh1;
      if (it < 16){
        int nt = wvi + it*4 + 4;
        nbh0 = w3bhi[(nt*2+0)*64 + lane];
        nbh1 = w3bhi[(nt*2+1)*64 + lane];
      }
      // ---- patch 0 ----
      {
        floatx4 a0 = {0.f,0.f,0.f,0.f};
        a0 = MFMA16(ahA[0], bh0, a0); a0 = MFMA16(ahA[1], bh1, a0);
        const float4 xA = *(const float4*)(xst0 + it*36 + rA);
        float den = 0.f, num = 0.f, e;
        e = fast_exp2(a0[0]); den += e; num = fmaf(e, xA.x, num);
        e = fast_exp2(a0[1]); den += e; num = fmaf(e, xA.y, num);
        e = fast_exp2(a0[2]); den += e; num = fmaf(e, xA.z, num);
        e = fast_exp2(a0[3]); den += e; num = fmaf(e, xA.w, num);
        if (two0){
          floatx4 a1 = {0.f,0.f,0.f,0.f};
          a1 = MFMA16(ahB[0], bh0, a1); a1 = MFMA16(ahB[1], bh1, a1);
          const float4 xB = *(const float4*)(xst0 + it*36 + rA + 16);
          e = fast_exp2(a1[0]); den += e; num = fmaf(e, xB.x, num);
          e = fast_exp2(a1[1]); den += e; num = fmaf(e, xB.y, num);
          e = fast_exp2(a1[2]); den += e; num = fmaf(e, xB.z, num);
          e = fast_exp2(a1[3]); den += e; num = fmaf(e, xB.w, num);
        }
        den += __shfl_xor(den, 16, 64); den += __shfl_xor(den, 32, 64);
        num += __shfl_xor(num, 16, 64); num += __shfl_xor(num, 32, 64);
        float res = (den > 0.f) ? num * fast_rcp(den) : xsum0[it] * (1.f/32.f);
        accA += res;
      }
      // ---- patch 1 ----
      {
        floatx4 a0 = {0.f,0.f,0.f,0.f};
        a0 = MFMA16(ahC[0], bh0, a0); a0 = MFMA16(ahC[1], bh1, a0);
        const float4 xA = *(const float4*)(xst1 + it*36 + rA);
        float den = 0.f, num = 0.f, e;
        e = fast_exp2(a0[0]); den += e; num = fmaf(e, xA.x, num);
        e = fast_exp2(a0[1]); den += e; num = fmaf(e, xA.y, num);
        e = fast_exp2(a0[2]); den += e; num = fmaf(e, xA.z, num);
        e = fast_exp2(a0[3]); den += e; num = fmaf(e, xA.w, num);
        if (two1){
          floatx4 a1 = {0.f,0.f,0.f,0.f};
          a1 = MFMA16(ahD[0], bh0, a1); a1 = MFMA16(ahD[1], bh1, a1);
          const float4 xB = *(const float4*)(xst1 + it*36 + rA + 16);
          e = fast_exp2(a1[0]); den += e; num = fmaf(e, xB.x, num);
          e = fast_exp2(a1[1]); den += e; num = fmaf(e, xB.y, num);
          e = fast_exp2(a1[2]); den += e; num = fmaf(e, xB.z, num);
          e = fast_exp2(a1[3]); den += e; num = fmaf(e, xB.w, num);
        }
        den += __shfl_xor(den, 16, 64); den += __shfl_xor(den, 32, 64);
        num += __shfl_xor(num, 16, 64); num += __shfl_xor(num, 32, 64);
        float res = (den > 0.f) ? num * fast_rcp(den) : xsum1[it] * (1.f/32.f);
        accB += res;
      }
    }
    if (quad == 0 && t_out < TT_){
      xp[p0*D_ + t_out] = fmaxf(accA + tb[t_out], 0.f);
      xp[p1*D_ + t_out] = fmaxf(accB + tb[t_out], 0.f);
    }
  }
  if (tid == 0){
    float mp0 = (V0 > 0) ? 1.f : 0.f;
    float mp1 = (V1 > 0) ? 1.f : 0.f;
    xp[p0*D_ + TT_] = mp0; pm[p0] = mp0;
    xp[p1*D_ + TT_] = mp1; pm[p1] = mp1;
  }
}

// -------------------------------------------------------------------------
// BOTH transformer layers fused, one block per bn — 512 threads (8 waves).
// R3: in-wave LayerNorm; fused FF-reduce + LN2 epilogue.
// R8: the l==1 epilogue atomically accumulates the mean-over-N directly into
// xsws (replaces the xout write + mean_kernel; xsws pre-zeroed by ttcn).
// -------------------------------------------------------------------------
__global__ __launch_bounds__(512) void layer12_kernel(
    const float* __restrict__ xin, const float* __restrict__ pm,
    const short8* __restrict__ frS,
    const float* __restrict__ gqb, const float* __restrict__ gkb,
    const float* __restrict__ gvb, const float* __restrict__ gob,
    const float* __restrict__ inb, const float* __restrict__ outb,
    const float* __restrict__ ln1g, const float* __restrict__ ln1b,
    const float* __restrict__ fb1, const float* __restrict__ fb2,
    const float* __restrict__ ln2g, const float* __restrict__ ln2b,
    float* __restrict__ xsws)
{
  __shared__ __align__(16) float xb[16*68];
  __shared__ __align__(16) float xb2[16*68];
  __shared__ __align__(16) float q_[16*68];
  __shared__ __align__(16) float k_[16*68];
  __shared__ __align__(16) float v_[16*68];
  __shared__ __align__(16) float ao[16*68];
  __shared__ __align__(16) float ss[1024];
  __shared__ __align__(16) short8 fragA[256];
  __shared__ __align__(16) float hbuf[8*16*36];
  __shared__ __align__(16) float part[8*16*68];
  __shared__ __align__(16) float pe_t[1024];
  __shared__ float tbt[16];
  __shared__ float pmv[16];

  const int bn = blockIdx.x, tid = threadIdx.x;
  const int lane = tid & 63, wvi = tid >> 6;        // wvi 0..7
  const int nidx = lane & 15, quad = lane >> 4;
  const float* xin_p = xin + bn*1024;

  for (int o = tid; o < 1024; o += 512) xb[(o>>6)*68 + (o&63)] = xin_p[o];
  if (tid < 16) pmv[tid] = pm[bn*16 + tid];
  for (int o = tid; o < 1024; o += 512){
    int tok = o >> 6, d = o & 63;
    float div = __expf((float)(d & ~1) * (-0.14391156831212793f)); // -ln(1e4)/64
    float arg = (float)tok * div;
    pe_t[o] = (d & 1) ? cosf(arg) : sinf(arg);
  }
  if (tid >= 32 && tid < 48) tbt[tid-32] = logf(expf(-5.0f*(float)(tid-32)) + 1e-12f);
  __syncthreads();

  for (int l = 0; l < 2; ++l){
    const int lbase = 9472 + l*36864;
    const float* gqbL = gqb + l*64;  const float* gkbL = gkb + l*64;
    const float* gvbL = gvb + l*64;  const float* gobL = gob + l*64;
    const float* inbL = inb + l*192; const float* outbL = outb + l*64;
    const float* ln1gL = ln1g + l*64; const float* ln1bL = ln1b + l*64;
    const float* fb1L = fb1 + l*2048; const float* fb2L = fb2 + l*64;
    const float* ln2gL = ln2g + l*64; const float* ln2bL = ln2b + l*64;

    // save layer input for the l==1 residual (rows wvi and wvi+8, d=lane)
    float xres[2];
    xres[0] = xb[wvi*68 + lane];
    xres[1] = xb[(wvi+8)*68 + lane];

    // ===== PREFETCH WAVE 1: gattn units u0=wvi,u1=wvi+8; MHA units same;
    //       gattn-out (waves 0-3). Unit u lives at base + u*128 (q/k/v packed).
    short8 gU0[4], gU1[4], mU0[4], mU1[4], ob4[4];
    {
      int b0 = lbase + wvi*128;
      gU0[0] = frS[b0 + lane];       gU0[1] = frS[FRAG_TOT + b0 + lane];
      gU0[2] = frS[b0 + 64 + lane];  gU0[3] = frS[FRAG_TOT + b0 + 64 + lane];
      int m0 = lbase + OFF_INW + wvi*128;
      mU0[0] = frS[m0 + lane];       mU0[1] = frS[FRAG_TOT + m0 + lane];
      mU0[2] = frS[m0 + 64 + lane];  mU0[3] = frS[FRAG_TOT + m0 + 64 + lane];
      if (wvi < 4){
        int b1 = lbase + (wvi+8)*128;
        gU1[0] = frS[b1 + lane];       gU1[1] = frS[FRAG_TOT + b1 + lane];
        gU1[2] = frS[b1 + 64 + lane];  gU1[3] = frS[FRAG_TOT + b1 + 64 + lane];
        int m1 = lbase + OFF_INW + (wvi+8)*128;
        mU1[0] = frS[m1 + lane];       mU1[1] = frS[FRAG_TOT + m1 + lane];
        mU1[2] = frS[m1 + 64 + lane];  mU1[3] = frS[FRAG_TOT + m1 + 64 + lane];
        int bo = lbase + 1536 + wvi*128;   // gow
        ob4[0] = frS[bo + lane];       ob4[1] = frS[FRAG_TOT + bo + lane];
        ob4[2] = frS[bo + 64 + lane];  ob4[3] = frS[FRAG_TOT + bo + 64 + lane];
      }
    }

    // ---- gattn QKV (12 tiles over 8 waves) ----
    packA68(xb, fragA, tid);
    __syncthreads();
    {
      short8 axh0 = fragA[lane], axh1 = fragA[64+lane];
      short8 axl0 = fragA[128+lane], axl1 = fragA[192+lane];
      {
        int u = wvi;                           // u 0..7: q (0-3), k (4-7)
        floatx4 c = {0.f,0.f,0.f,0.f};
        c = mm3(axh0, axl0, gU0[0], gU0[1], c);
        c = mm3(axh1, axl1, gU0[2], gU0[3], c);
        int sel = u >> 2, d = (u & 3)*16 + nidx;
        float bb = (sel == 0 ? gqbL : gkbL)[d];
        float* dst = (sel == 0 ? q_ : k_);
        #pragma unroll
        for (int r = 0; r < 4; ++r) dst[(quad*4+r)*68 + d] = c[r] + bb;
      }
      if (wvi < 4){
        int u = wvi + 8;                       // u 8..11: v
        floatx4 c = {0.f,0.f,0.f,0.f};
        c = mm3(axh0, axl0, gU1[0], gU1[1], c);
        c = mm3(axh1, axl1, gU1[2], gU1[3], c);
        int d = (u & 3)*16 + nidx;
        float bb = gvbL[d];
        #pragma unroll
        for (int r = 0; r < 4; ++r) v_[(quad*4+r)*68 + d] = c[r] + bb;
      }
    }
    __syncthreads();
    // ---- merged scores+softmax (64 rows x 8 lanes, all 512 threads) ----
    {
      int row = tid >> 3;                 // h*16+qm
      int h = row >> 4, qm = row & 15;
      int km0 = (tid & 7) * 2;
      float s2[2];
      #pragma unroll
      for (int j = 0; j < 2; ++j){
        int km = km0 + j;
        float acc = dot16(q_ + qm*68 + h*16, k_ + km*68 + h*16);
        int dd = qm - km; if (dd < 0) dd = -dd;
        acc = acc * 0.25f + tbt[dd];
        if (pmv[km] == 0.f) acc = -1e9f;
        s2[j] = acc;
      }
      float mx = fmaxf(s2[0], s2[1]);
      mx = fmaxf(mx, __shfl_xor(mx, 1, 64));
      mx = fmaxf(mx, __shfl_xor(mx, 2, 64));
      mx = fmaxf(mx, __shfl_xor(mx, 4, 64));
      float e2[2], se = 0.f;
      #pragma unroll
      for (int j = 0; j < 2; ++j){ e2[j] = __expf(s2[j]-mx); se += e2[j]; }
      se += __shfl_xor(se, 1, 64);
      se += __shfl_xor(se, 2, 64);
      se += __shfl_xor(se, 4, 64);
      float inv = fast_rcp(se);
      #pragma unroll
      for (int j = 0; j < 2; ++j) ss[row*16 + km0 + j] = e2[j]*inv;
    }
    __syncthreads();
    for (int o = tid; o < 1024; o += 512){
      int m = o >> 6, d = o & 63, h = d >> 4;
      float acc = 0.f;
      #pragma unroll
      for (int km = 0; km < 16; ++km) acc += ss[h*256 + m*16 + km] * v_[km*68 + d];
      ao[m*68 + d] = acc;
    }
    __syncthreads();
    packA68(ao, fragA, tid);
    __syncthreads();
    if (wvi < 4){
      short8 axh0 = fragA[lane], axh1 = fragA[64+lane];
      short8 axl0 = fragA[128+lane], axl1 = fragA[192+lane];
      floatx4 c = {0.f,0.f,0.f,0.f};
      c = mm3(axh0, axl0, ob4[0], ob4[1], c);
      c = mm3(axh1, axl1, ob4[2], ob4[3], c);
      int d = wvi*16 + nidx;
      float bb = gobL[d];
      #pragma unroll
      for (int r = 0; r < 4; ++r){
        int tok = quad*4 + r;
        xb[tok*68 + d] += (c[r] + bb) * pmv[tok] + pe_t[tok*64 + d];
      }
    }
    __syncthreads();

    // ===== PREFETCH WAVE 2: MHA-out (waves 0-3) + FF f1/f2 initial (8 waves)
    short8 mob[4], f1c[4], f2c[4];
    if (wvi < 4){
      int base = lbase + OFF_OUTW + wvi*128;
      mob[0] = frS[base + lane];       mob[1] = frS[FRAG_TOT + base + lane];
      mob[2] = frS[base + 64 + lane];  mob[3] = frS[FRAG_TOT + base + 64 + lane];
    }
    {
      int f1base = lbase + OFF_FW1, f2base = lbase + OFF_FW2;
      #pragma unroll
      for (int t2 = 0; t2 < 2; ++t2){
        int sb = f1base + ((wvi*16+t2)*2)*64 + lane;
        f1c[t2*2+0] = frS[sb];
        f1c[t2*2+1] = frS[sb + 64];
      }
      #pragma unroll
      for (int ntd = 0; ntd < 4; ++ntd)
        f2c[ntd] = frS[f2base + (ntd*64 + wvi*8)*64 + lane];
    }

    // ---- MHA QKV (12 tiles over 8 waves) ----
    packA68(xb, fragA, tid);
    __syncthreads();
    {
      short8 axh0 = fragA[lane], axh1 = fragA[64+lane];
      short8 axl0 = fragA[128+lane], axl1 = fragA[192+lane];
      {
        int u = wvi;
        floatx4 c = {0.f,0.f,0.f,0.f};
        c = mm3(axh0, axl0, mU0[0], mU0[1], c);
        c = mm3(axh1, axl1, mU0[2], mU0[3], c);
        int sel = u >> 2, d = (u & 3)*16 + nidx;
        float bb = inbL[u*16 + nidx];
        float* dst = (sel == 0 ? q_ : k_);
        #pragma unroll
        for (int r = 0; r < 4; ++r) dst[(quad*4+r)*68 + d] = c[r] + bb;
      }
      if (wvi < 4){
        int u = wvi + 8;
        floatx4 c = {0.f,0.f,0.f,0.f};
        c = mm3(axh0, axl0, mU1[0], mU1[1], c);
        c = mm3(axh1, axl1, mU1[2], mU1[3], c);
        int d = (u & 3)*16 + nidx;
        float bb = inbL[u*16 + nidx];
        #pragma unroll
        for (int r = 0; r < 4; ++r) v_[(quad*4+r)*68 + d] = c[r] + bb;
      }
    }
    __syncthreads();
    {
      int row = tid >> 3;
      int h = row >> 4, qm = row & 15;
      int km0 = (tid & 7) * 2;
      float s2[2];
      #pragma unroll
      for (int j = 0; j < 2; ++j)
        s2[j] = 0.25f * dot16(q_ + qm*68 + h*16, k_ + (km0+j)*68 + h*16);
      float mx = fmaxf(s2[0], s2[1]);
      mx = fmaxf(mx, __shfl_xor(mx, 1, 64));
      mx = fmaxf(mx, __shfl_xor(mx, 2, 64));
      mx = fmaxf(mx, __shfl_xor(mx, 4, 64));
      float e2[2], se = 0.f;
      #pragma unroll
      for (int j = 0; j < 2; ++j){ e2[j] = __expf(s2[j]-mx); se += e2[j]; }
      se += __shfl_xor(se, 1, 64);
      se += __shfl_xor(se, 2, 64);
      se += __shfl_xor(se, 4, 64);
      float inv = fast_rcp(se);
      #pragma unroll
      for (int j = 0; j < 2; ++j) ss[row*16 + km0 + j] = e2[j]*inv;
    }
    __syncthreads();
    for (int o = tid; o < 1024; o += 512){
      int m = o >> 6, d = o & 63, h = d >> 4;
      float acc = 0.f;
      #pragma unroll
      for (int km = 0; km < 16; ++km) acc += ss[h*256 + m*16 + km] * v_[km*68 + d];
      ao[m*68 + d] = acc;
    }
    __syncthreads();
    packA68(ao, fragA, tid);
    __syncthreads();
    if (wvi < 4){
      short8 axh0 = fragA[lane], axh1 = fragA[64+lane];
      short8 axl0 = fragA[128+lane], axl1 = fragA[192+lane];
      floatx4 c = {0.f,0.f,0.f,0.f};
      c = mm3(axh0, axl0, mob[0], mob[1], c);
      c = mm3(axh1, axl1, mob[2], mob[3], c);
      int d = wvi*16 + nidx;
      float bb = outbL[d];
      #pragma unroll
      for (int r = 0; r < 4; ++r) xb[(quad*4+r)*68 + d] += c[r] + bb;
    }
    __syncthreads();

    // ---- LN1: in-wave (wave w -> tokens w, w+8; lane = d) -> xb2 ----
    {
      float a = xb[wvi*68 + lane], b = xb[(wvi+8)*68 + lane];
      float mua = wsum64(a) * (1.f/64.f);
      float mub = wsum64(b) * (1.f/64.f);
      float da = a - mua, db = b - mub;
      float va = wsum64(da*da) * (1.f/64.f);
      float vb = wsum64(db*db) * (1.f/64.f);
      float rva = rsqrtf(va + 1e-5f), rvb = rsqrtf(vb + 1e-5f);
      float g = ln1gL[lane], bia = ln1bL[lane];
      xb2[wvi*68 + lane]     = da*rva*g + bia;
      xb2[(wvi+8)*68 + lane] = db*rvb*g + bia;
    }
    __syncthreads();
    packA68(xb2, fragA, tid);
    __syncthreads();

    // ---- FF (2048 hidden over 8 waves, 8 iters each); f1/f2 prefetch 1 ahead
    {
      const int w = wvi;
      const int f1base = lbase + OFF_FW1, f2base = lbase + OFF_FW2;
      short8 axh0 = fragA[lane], axh1 = fragA[64 + lane];
      floatx4 y0 = {0.f,0.f,0.f,0.f}, y1 = y0, y2 = y0, y3 = y0;
      float* hw = hbuf + w*576;

      short8 f1n[4], f2n[4];
      for (int it = 0; it < 8; ++it){
        int ntA = w*16 + it*2;
        floatx4 hA = {0.f,0.f,0.f,0.f}, hB = hA;
        hA = MFMA16(axh0, f1c[0], hA); hA = MFMA16(axh1, f1c[1], hA);
        hB = MFMA16(axh0, f1c[2], hB); hB = MFMA16(axh1, f1c[3], hB);
        float bbA = fb1L[ntA*16 + nidx], bbB = fb1L[ntA*16 + 16 + nidx];
        #pragma unroll
        for (int r = 0; r < 4; ++r){
          hw[(quad*4+r)*36 + nidx]      = fmaxf(hA[r] + bbA, 0.f);
          hw[(quad*4+r)*36 + 16 + nidx] = fmaxf(hB[r] + bbB, 0.f);
        }
        if (it < 7){
          int ntN = ntA + 2, kstN = w*8 + it + 1;
          #pragma unroll
          for (int t2 = 0; t2 < 2; ++t2){
            int sb = f1base + ((ntN+t2)*2)*64 + lane;
            f1n[t2*2+0] = frS[sb];
            f1n[t2*2+1] = frS[sb + 64];
          }
          #pragma unroll
          for (int ntd = 0; ntd < 4; ++ntd)
            f2n[ntd] = frS[f2base + (ntd*64 + kstN)*64 + lane];
        }
        short8 ah = cvt8s(hw + (lane & 15)*36 + quad*8);
        y0 = MFMA16(ah, f2c[0], y0);
        y1 = MFMA16(ah, f2c[1], y1);
        y2 = MFMA16(ah, f2c[2], y2);
        y3 = MFMA16(ah, f2c[3], y3);
        #pragma unroll
        for (int j = 0; j < 4; ++j){ f1c[j] = f1n[j]; f2c[j] = f2n[j]; }
      }
      #pragma unroll
      for (int r = 0; r < 4; ++r){
        int row = (quad*4 + r)*68;
        part[w*1088 + row + nidx]      = y0[r];
        part[w*1088 + row + 16 + nidx] = y1[r];
        part[w*1088 + row + 32 + nidx] = y2[r];
        part[w*1088 + row + 48 + nidx] = y3[r];
      }
    }
    __syncthreads();
    // ---- FF part-reduce + fb2 + LN2 + residual; l==1 -> atomic mean ----
    {
      float ra = xb2[wvi*68 + lane] + fb2L[lane];
      float rb = xb2[(wvi+8)*68 + lane] + fb2L[lane];
      #pragma unroll
      for (int ww = 0; ww < 8; ++ww){
        ra += part[ww*1088 + wvi*68 + lane];
        rb += part[ww*1088 + (wvi+8)*68 + lane];
      }
      float mua = wsum64(ra) * (1.f/64.f);
      float mub = wsum64(rb) * (1.f/64.f);
      float da = ra - mua, db = rb - mub;
      float va = wsum64(da*da) * (1.f/64.f);
      float vb = wsum64(db*db) * (1.f/64.f);
      float rva = rsqrtf(va + 1e-5f), rvb = rsqrtf(vb + 1e-5f);
      float g = ln2gL[lane], bia = ln2bL[lane];
      float vva = da*rva*g + bia;
      float vvb = db*rvb*g + bia;
      if (l == 0){
        xb[wvi*68 + lane]     = vva;               // becomes layer-1 input
        xb[(wvi+8)*68 + lane] = vvb;
      } else {
        int b = bn >> 5;                            // N_ = 32
        atomicAdd(&xsws[(b*M_ + wvi)*64 + lane],     (vva + xres[0]) * (1.f/32.f));
        atomicAdd(&xsws[(b*M_ + wvi + 8)*64 + lane], (vvb + xres[1]) * (1.f/32.f));
      }
    }
    __syncthreads();
  }
}

// -------------------------------------------------------------------------
// Classifier head. One block per b. (small; fp32). xs = mean over N,
// accumulated atomically by layer12 (R8).
// -------------------------------------------------------------------------
__global__ __launch_bounds__(256) void final_kernel(
    const float* __restrict__ xsws, const float* __restrict__ pm,
    const float* __restrict__ q_embed,
    const float* __restrict__ cin_w, const float* __restrict__ cin_b,
    const float* __restrict__ cout_w, const float* __restrict__ cout_b,
    const float* __restrict__ logit_w, const float* __restrict__ logit_b,
    float* __restrict__ out)
{
  const int b = blockIdx.x;
  const int tid = threadIdx.x;
  __shared__ __align__(16) float xs[M_ * D_];
  __shared__ float kpmv[M_];
  __shared__ __align__(16) float qv[5 * D_], kv[M_ * D_], vv[M_ * D_];
  __shared__ float sv[H_ * 5 * M_];
  __shared__ __align__(16) float ao[5 * D_], zv[5 * D_];

  for (int o = tid; o < M_ * D_; o += 256) xs[o] = xsws[b*M_*D_ + o];
  if (tid < M_) {
    float any = 0.f;
    #pragma unroll
    for (int n = 0; n < N_; ++n) any += (pm[(b * N_ + n) * M_ + tid] > 0.f) ? 1.f : 0.f;
    kpmv[tid] = (any > 0.f) ? 0.f : 1.f;
  }
  __syncthreads();

  for (int o = tid; o < 5 * D_; o += 256) {
    int qi = o >> 6, d = o & 63;
    qv[o] = cin_b[d] + dot64(q_embed + qi * D_, cin_w + d * D_);
  }
  for (int o = tid; o < 2 * M_ * D_; o += 256) {
    int sel = o >> 10, r = o & 1023, m = r >> 6, d = r & 63;
    float acc = cin_b[D_ + sel * D_ + d] + dot64(xs + m * D_, cin_w + (D_ + sel * D_ + d) * D_);
    ((sel == 0) ? kv : vv)[r] = acc;
  }
  __syncthreads();

  for (int o = tid; o < H_ * 5 * M_; o += 256) {
    int h = o / 80, r = o % 80, qi = r >> 4, km = r & 15;
    float acc = 0.25f * dot16(qv + qi * D_ + h * DH_, kv + km * D_ + h * DH_);
    if (kpmv[km] != 0.f) acc = -1e9f;
    sv[o] = acc;
  }
  __syncthreads();
  if (tid < H_ * 5) {
    int h = tid / 5, qi = tid % 5;
    float* row = sv + h * 80 + qi * M_;
    float mx = -1e30f;
    #pragma unroll
    for (int km = 0; km < M_; ++km) mx = fmaxf(mx, row[km]);
    float se = 0.f;
    #pragma unroll
    for (int km = 0; km < M_; ++km) { float e = __expf(row[km] - mx); row[km] = e; se += e; }
    float inv = 1.f / se;
    #pragma unroll
    for (int km = 0; km < M_; ++km) row[km] *= inv;
  }
  __syncthreads();
  for (int o = tid; o < 5 * D_; o += 256) {
    int qi = o >> 6, d = o & 63, h = d >> 4;
    float acc = 0.f;
    #pragma unroll
    for (int km = 0; km < M_; ++km) acc += sv[h * 80 + qi * M_ + km] * vv[km * D_ + d];
    ao[o] = acc;
  }
  __syncthreads();
  for (int o = tid; o < 5 * D_; o += 256) {
    int qi = o >> 6, d = o & 63;
    zv[o] = cout_b[d] + dot64(ao + qi * D_, cout_w + d * D_);
  }
  __syncthreads();
  if (tid < 5) {
    float acc = logit_b[0] + dot64(zv + tid * D_, logit_w);
    out[b * 5 + tid] = acc;
  }
}

// -------------------------------------------------------------------------
extern "C" void kernel_launch(void* const* d_in, const int* in_sizes, int n_in,
                              void* d_out, int out_size, void* d_ws, size_t ws_size,
                              hipStream_t stream) {
  const float* x       = (const float*)d_in[0];
  const int*   mask    = (const int*)  d_in[1];
  const float* ttcn_w1 = (const float*)d_in[2];
  const float* ttcn_b1 = (const float*)d_in[3];
  const float* ttcn_w2 = (const float*)d_in[4];
  const float* ttcn_b2 = (const float*)d_in[5];
  const float* ttcn_w3 = (const float*)d_in[6];
  const float* ttcn_b3 = (const float*)d_in[7];   // unused: cancels in softmax
  const float* t_bias  = (const float*)d_in[8];
  const float* ga_qw   = (const float*)d_in[9];
  const float* ga_qb   = (const float*)d_in[10];
  const float* ga_kw   = (const float*)d_in[11];
  const float* ga_kb   = (const float*)d_in[12];
  const float* ga_vw   = (const float*)d_in[13];
  const float* ga_vb   = (const float*)d_in[14];
  const float* ga_ow   = (const float*)d_in[15];
  const float* ga_ob   = (const float*)d_in[16];
  const float* tf_in_w = (const float*)d_in[17];
  const float* tf_in_b = (const float*)d_in[18];
  const float* tf_out_w= (const float*)d_in[19];
  const float* tf_out_b= (const float*)d_in[20];
  const float* tf_ln1g = (const float*)d_in[21];
  const float* tf_ln1b = (const float*)d_in[22];
  const float* tf_ln2g = (const float*)d_in[23];
  const float* tf_ln2b = (const float*)d_in[24];
  const float* tf_fw1  = (const float*)d_in[25];
  const float* tf_fb1  = (const float*)d_in[26];
  const float* tf_fw2  = (const float*)d_in[27];
  const float* tf_fb2  = (const float*)d_in[28];
  const float* q_embed = (const float*)d_in[29];
  const float* cls_in_w  = (const float*)d_in[30];
  const float* cls_in_b  = (const float*)d_in[31];
  const float* cls_out_w = (const float*)d_in[32];
  const float* cls_out_b = (const float*)d_in[33];
  const float* logit_w = (const float*)d_in[34];
  const float* logit_b = (const float*)d_in[35];
  (void)ttcn_b3;

  float* wsf  = (float*)d_ws;
  float* xp   = wsf;                        // 262144 f
  float* pmb  = wsf + P_TOT * D_;           // 4096 f
  uint4* fr   = (uint4*)(pmb + P_TOT);      // 2*FRAG_TOT uint4
  float* xsws = (float*)(fr + 2*FRAG_TOT);  // 8192 f (atomic mean over N)
  const short8* frS = (const short8*)fr;

  prep_kernel<<<325, 256, 0, stream>>>(ttcn_w1, ttcn_w2, ttcn_w3,
      ga_qw, ga_kw, ga_vw, ga_ow, tf_in_w, tf_out_w, tf_fw1, tf_fw2, fr);

  ttcn_kernel<<<P_TOT/2, 256, 0, stream>>>(x, mask, ttcn_b1, ttcn_b2, t_bias,
      frS + 0, frS + 256, frS + 768,
      xp, pmb, xsws);

  layer12_kernel<<<BN_, 512, 0, stream>>>(xp, pmb, frS,
      ga_qb, ga_kb, ga_vb, ga_ob, tf_in_b, tf_out_b, tf_ln1g, tf_ln1b,
      tf_fb1, tf_fb2, tf_ln2g, tf_ln2b, xsws);

  final_kernel<<<B_, 256, 0, stream>>>(xsws, pmb, q_embed,
                                       cls_in_w, cls_in_b, cls_out_w, cls_out_b,
                                       logit_w, logit_b, (float*)d_out);
}

// Round 10
// 223.610 us; speedup vs baseline: 1.0369x; 1.0369x over previous
//
#include <hip/hip_runtime.h>
#include <hip/hip_bf16.h>
#include <math.h>

// Problem constants
#define B_  8
#define N_  32
#define M_  16
#define LX  32
#define D_  64
#define IN_DIM_ 17
#define TT_ 63
#define H_  4
#define DH_ 16
#define P_TOT 4096          // B*N*M
#define BN_ 256             // B*N
#define FF_ 2048

// Fragment pool layout (slot = one short8/uint4 per lane-group entry)
#define FRAG_TOT 83200
#define OFF_INW  2048
#define OFF_OUTW 3584
#define OFF_FW1  4096
#define OFF_FW2  20480

typedef unsigned short ushort_t;
typedef __attribute__((ext_vector_type(8))) short short8;   // 8 bf16 (4 VGPRs)
typedef __attribute__((ext_vector_type(4))) float floatx4;  // MFMA C/D

#define MFMA16(a,b,c) __builtin_amdgcn_mfma_f32_16x16x32_bf16((a),(b),(c),0,0,0)

__device__ __forceinline__ float fast_exp2(float x){
#if __has_builtin(__builtin_amdgcn_exp2f)
  return __builtin_amdgcn_exp2f(x);
#else
  return __expf(x * 0.6931471805599453f);
#endif
}
__device__ __forceinline__ float fast_rcp(float x){
#if __has_builtin(__builtin_amdgcn_rcpf)
  return __builtin_amdgcn_rcpf(x);
#else
  return 1.0f / x;
#endif
}

__device__ __forceinline__ ushort_t f2bf(float f){          // RNE float->bf16
  unsigned u = __float_as_uint(f);
  u += 0x7FFFu + ((u >> 16) & 1u);
  return (ushort_t)(u >> 16);
}
__device__ __forceinline__ float bf2f(ushort_t h){ return __uint_as_float(((unsigned)h) << 16); }

__device__ __forceinline__ uint4 pack8(const ushort_t* h){
  uint4 u;
  u.x = (unsigned)h[0] | ((unsigned)h[1] << 16);
  u.y = (unsigned)h[2] | ((unsigned)h[3] << 16);
  u.z = (unsigned)h[4] | ((unsigned)h[5] << 16);
  u.w = (unsigned)h[6] | ((unsigned)h[7] << 16);
  return u;
}

// split 8 consecutive floats into hi/lo bf16 short8
__device__ __forceinline__ void split8(const float* r, short8& hi, short8& lo){
  #pragma unroll
  for (int j = 0; j < 8; ++j){
    float v = r[j];
    ushort_t h = f2bf(v);
    ushort_t l2 = f2bf(v - bf2f(h));
    hi[j] = (short)h; lo[j] = (short)l2;
  }
}
// hi-only conversion -> uint4
__device__ __forceinline__ uint4 cvt8(const float* r){
  ushort_t hh[8];
  #pragma unroll
  for (int j = 0; j < 8; ++j) hh[j] = f2bf(r[j]);
  return pack8(hh);
}
// hi-only conversion -> short8
__device__ __forceinline__ short8 cvt8s(const float* r){
  union { uint4 u4; short8 s8; } cv;
  cv.u4 = cvt8(r);
  return cv.s8;
}

// 3-term split product: (ah+al)(bh+bl) ~= ah*bh + ah*bl + al*bh
__device__ __forceinline__ floatx4 mm3(short8 ah, short8 al, short8 bh, short8 bl, floatx4 c){
  c = MFMA16(ah, bh, c); c = MFMA16(ah, bl, c); c = MFMA16(al, bh, c); return c;
}

__device__ __forceinline__ float dot64(const float* __restrict__ a, const float* __restrict__ w){
  const float4* a4 = (const float4*)a;
  const float4* w4 = (const float4*)w;
  float acc = 0.f;
  #pragma unroll
  for (int k = 0; k < 16; ++k){ float4 x = a4[k], y = w4[k];
    acc += x.x*y.x + x.y*y.y + x.z*y.z + x.w*y.w; }
  return acc;
}
__device__ __forceinline__ float dot16(const float* __restrict__ a, const float* __restrict__ b){
  const float4* a4 = (const float4*)a; const float4* b4 = (const float4*)b;
  float acc = 0.f;
  #pragma unroll
  for (int k = 0; k < 4; ++k){ float4 x = a4[k], y = b4[k];
    acc += x.x*y.x + x.y*y.y + x.z*y.z + x.w*y.w; }
  return acc;
}

// pack A-frags (16 tokens x 64 k) from stride-68 LDS buffer into fragA (hi[128], lo[128])
__device__ __forceinline__ void packA68(const float* buf, short8* fA, int tid){
  if (tid < 128){
    int ln = tid & 63, ks = tid >> 6;
    const float* r = buf + (ln & 15)*68 + ks*32 + ((ln >> 4) & 3)*8;
    short8 hi, lo; split8(r, hi, lo);
    fA[tid] = hi; fA[128 + tid] = lo;
  }
}

// in-wave 64-lane sum reduction (6 shfl)
__device__ __forceinline__ float wsum64(float v){
  v += __shfl_xor(v, 1, 64);  v += __shfl_xor(v, 2, 64);
  v += __shfl_xor(v, 4, 64);  v += __shfl_xor(v, 8, 64);
  v += __shfl_xor(v, 16, 64); v += __shfl_xor(v, 32, 64);
  return v;
}

// -------------------------------------------------------------------------
// Prep: convert ALL weight matrices to MFMA B-fragment pool (hi at [s], lo at
// [FRAG_TOT+s]; lo only written for attn segments — ttcn + FF consume hi only).
// B[k][n]: n = nt*16 + (lane&15), k = ks*32 + quad*8 + j.
// w3 special: (a) columns reordered so tile nt covers i = nt>>2 (constant per
// tile), t = (nt&3)*16 + lane&15; (b) k=63 slot = 1.0 (mask carrier);
// (c) ALL w3 values scaled by log2(e) so epilogue uses raw v_exp_f32.
// -------------------------------------------------------------------------
__global__ __launch_bounds__(256) void prep_kernel(
    const float* __restrict__ w1, const float* __restrict__ w2, const float* __restrict__ w3,
    const float* __restrict__ gqw, const float* __restrict__ gkw,
    const float* __restrict__ gvw, const float* __restrict__ gow,
    const float* __restrict__ inw, const float* __restrict__ outw,
    const float* __restrict__ fw1, const float* __restrict__ fw2,
    uint4* __restrict__ fr)
{
  int s = blockIdx.x*256 + threadIdx.x;
  if (s >= FRAG_TOT) return;
  const float* src; int Nr, Kr, KS, rel; int w3seg = 0, noLo = 0;
  if (s < 256)      { src = w1; Nr=63;  Kr=17; KS=1; rel = s; noLo = 1; }
  else if (s < 768) { src = w2; Nr=63;  Kr=63; KS=2; rel = s-256; noLo = 1; }
  else if (s < 9472){ src = w3; Nr=1071;Kr=63; KS=2; rel = s-768; w3seg = 1; noLo = 1; }
  else {
    int t = s - 9472, l = t / 36864, r2 = t - l*36864;
    if (r2 < 512)        { src = gqw + l*4096;   Nr=64;  Kr=64;   KS=2;  rel = r2; }
    else if (r2 < 1024)  { src = gkw + l*4096;   Nr=64;  Kr=64;   KS=2;  rel = r2-512; }
    else if (r2 < 1536)  { src = gvw + l*4096;   Nr=64;  Kr=64;   KS=2;  rel = r2-1024; }
    else if (r2 < 2048)  { src = gow + l*4096;   Nr=64;  Kr=64;   KS=2;  rel = r2-1536; }
    else if (r2 < 3584)  { src = inw + l*12288;  Nr=192; Kr=64;   KS=2;  rel = r2-2048; }
    else if (r2 < 4096)  { src = outw + l*4096;  Nr=64;  Kr=64;   KS=2;  rel = r2-3584; }
    else if (r2 < 20480) { src = fw1 + l*131072; Nr=2048;Kr=64;   KS=2;  rel = r2-4096; noLo = 1; }
    else                 { src = fw2 + l*131072; Nr=64;  Kr=2048; KS=64; rel = r2-20480; noLo = 1; }
  }
  int lane = rel & 63, tmp = rel >> 6;
  int ks = tmp % KS, nt = tmp / KS;
  int kb = ks*32 + ((lane >> 4) & 3)*8;
  int n, validn;
  if (w3seg){
    int i = nt >> 2, tq = nt & 3;
    int t = tq*16 + (lane & 15);
    n = t*17 + i;                         // source row of w3 (c = t*17+i)
    validn = (t < 63);
  } else {
    n = nt*16 + (lane & 15);
    validn = (n < Nr);
  }
  float v[8];
  #pragma unroll
  for (int j = 0; j < 8; ++j){
    v[j] = (validn && (kb + j) < Kr) ? src[n*Kr + kb + j] : 0.f;
    if (w3seg){
      if ((kb + j) == 63) v[j] = 1.0f;               // mask-carrier column
      v[j] *= 1.4426950408889634f;                   // log2(e) for exp2 epilogue
    }
  }
  ushort_t hh[8];
  #pragma unroll
  for (int j = 0; j < 8; ++j) hh[j] = f2bf(v[j]);
  fr[s] = pack8(hh);
  if (!noLo){
    ushort_t ll[8];
    #pragma unroll
    for (int j = 0; j < 8; ++j) ll[j] = f2bf(v[j] - bf2f(hh[j]));
    fr[FRAG_TOT + s] = pack8(ll);
  }
}

// -------------------------------------------------------------------------
// Fused TTCN — bf16 1-term MFMA, h1/h2 stored directly as bf16 [cl][t].
// R1: valid-row compaction (ballot-scan; V<=16 -> single 16-row tile).
// R4/R7/R8 form — PROVEN best (43.7 µs). R10: reverted R9's 2-patch ILP
// (occupancy 48->30%, regressed). ttcn restructurings exhausted: 512-thread
// split, depth-2 prefetch, 2-patch ILP all neutral/negative; this is the
// structural floor for this code shape.
// -------------------------------------------------------------------------
__global__ __launch_bounds__(256) void ttcn_kernel(
    const float* __restrict__ x, const int* __restrict__ mask,
    const float* __restrict__ b1, const float* __restrict__ b2,
    const float* __restrict__ tb,
    const short8* __restrict__ w1bhi,
    const short8* __restrict__ w2bhi,
    const short8* __restrict__ w3bhi,
    float* __restrict__ xp, float* __restrict__ pm,
    float* __restrict__ xsws)
{
  __shared__ __align__(16) char pool[16512];
  float*    xs    = (float*)(pool + 0);        // 32x20 f (row l, stride 20)
  float*    xst   = (float*)(pool + 2560);     // 17x36 f (row i, COMPACTED l)
  int*      cmap  = (int*)  (pool + 5008);     // 32 ints: compact slot -> orig l
  float*    xsumv = (float*)(pool + 5136);     // 17 f (+pad)
  int*      Vp    = (int*)  (pool + 5204);     // valid-row count
  short8*   xfhi  = (short8*)(pool + 5216);    // 128 slots
  ushort_t* h1t   = (ushort_t*)(pool + 7264);  // 32x72 bf16 [cl][t] (dead after P4)
  ushort_t* h2t   = (ushort_t*)(pool + 11872); // 32x72 bf16 [cl][t]

  const int p = blockIdx.x, tid = threadIdx.x;
  const int lane = tid & 63, wvi = tid >> 6;
  const int nidx = lane & 15, quad = lane >> 4;

  // zero the atomic-mean accumulator (128 blocks x 64 floats)
  if (p < 128 && tid < 64) xsws[p*64 + tid] = 0.f;

  // P0: stage x (stride 20) + mask ballot-scan (wave 0)
  for (int idx = tid; idx < LX*IN_DIM_; idx += 256){
    int l = (idx * 3856) >> 16;             // idx/17 exact for idx<1088
    int i = idx - l*17;
    xs[l*20 + i] = x[p*(LX*IN_DIM_) + idx];
  }
  if (tid < 64){
    int mv = (tid < 32) ? mask[p*LX + tid] : 0;
    unsigned long long bal = __ballot(mv != 0);
    if (tid < 32) cmap[tid] = 0;                 // default: padded rows -> row 0
    int pos = __popcll(bal & ((1ull << tid) - 1ull));
    if (mv != 0) cmap[pos] = tid;
    if (tid == 0) *Vp = (int)__popcll(bal);
  }
  __syncthreads();
  const int V   = *Vp;
  const int two = (V > 16);                      // need second 16-row tile?

  // P1: x A-fragments (hi only, COMPACTED rows) on threads <128;
  //     xsumv (original rows, fallback) + compacted xst on the rest
  if (tid < 128){
    int mt = tid >> 6;
    if (mt == 0 || two){
      int lc = cmap[mt*16 + nidx];
      float r[8];
      #pragma unroll
      for (int j = 0; j < 8; ++j){
        int k = quad*8 + j;
        r[j] = (k < IN_DIM_) ? xs[lc*20 + k] : 0.f;
      }
      ((uint4*)xfhi)[tid] = cvt8(r);
    }
  } else {
    if (tid < 128 + IN_DIM_){
      int i = tid - 128;
      float s = 0.f;
      #pragma unroll
      for (int l = 0; l < LX; ++l) s += xs[l*20 + i];
      xsumv[i] = s;
    }
    if (two){
      for (int idx = tid - 128; idx < 544; idx += 128){
        int i = idx >> 5, cl = idx & 31;
        xst[i*36 + cl] = xs[cmap[cl]*20 + i];
      }
    } else {
      for (int idx = tid - 128; idx < 272; idx += 128){
        int i = idx >> 4, cl = idx & 15;
        xst[i*36 + cl] = xs[cmap[cl]*20 + i];
      }
    }
  }
  __syncthreads();

  // P2: GEMM1  h1 = relu(x @ w1^T + b1) -> bf16 [cl][t] stride 72
  {
    short8 axh0 = xfhi[lane];
    short8 bh = w1bhi[wvi*64 + lane];
    floatx4 a0 = {0.f,0.f,0.f,0.f};
    a0 = MFMA16(axh0, bh, a0);
    int t = wvi*16 + nidx;
    float bb = (t < TT_) ? b1[t] : 0.f;
    if (two){
      short8 axh1 = xfhi[64 + lane];
      floatx4 a1 = {0.f,0.f,0.f,0.f};
      a1 = MFMA16(axh1, bh, a1);
      #pragma unroll
      for (int r = 0; r < 4; ++r)
        h1t[(16+quad*4+r)*72 + t] = f2bf(fmaxf(a1[r] + bb, 0.f));
    }
    #pragma unroll
    for (int r = 0; r < 4; ++r)
      h1t[(quad*4+r)*72 + t] = f2bf(fmaxf(a0[r] + bb, 0.f));
  }
  __syncthreads();

  // P4: GEMM2  h2 = relu(h1 @ w2^T + b2); A-frags = direct b128 from h1t
  {
    short8 bh0 = w2bhi[(wvi*2+0)*64 + lane];
    short8 bh1 = w2bhi[(wvi*2+1)*64 + lane];
    short8 a00 = *(const short8*)((const char*)h1t + (nidx*72 + quad*8)*2);
    short8 a01 = *(const short8*)((const char*)h1t + (nidx*72 + 32 + quad*8)*2);
    floatx4 a0 = {0.f,0.f,0.f,0.f};
    a0 = MFMA16(a00, bh0, a0); a0 = MFMA16(a01, bh1, a0);
    int t = wvi*16 + nidx;
    float bb = (t < TT_) ? b2[t] : 0.f;
    if (two){
      short8 a10 = *(const short8*)((const char*)h1t + ((16+nidx)*72 + quad*8)*2);
      short8 a11 = *(const short8*)((const char*)h1t + ((16+nidx)*72 + 32 + quad*8)*2);
      floatx4 a1 = {0.f,0.f,0.f,0.f};
      a1 = MFMA16(a10, bh0, a1); a1 = MFMA16(a11, bh1, a1);
      #pragma unroll
      for (int r = 0; r < 4; ++r)
        h2t[(16+quad*4+r)*72 + t] = f2bf(fmaxf(a1[r] + bb, 0.f));
    }
    #pragma unroll
    for (int r = 0; r < 4; ++r)
      h2t[(quad*4+r)*72 + t] = f2bf(fmaxf(a0[r] + bb, 0.f));
  }
  __syncthreads();

  // P6: GEMM3 (i-major tiles; carrier + log2e folded into MFMA) + softmax +
  // contract + in-register h_t accumulation (i = it, t_out fixed per lane).
  // One- or two-tile variant chosen block-uniformly by V. Full unroll (R8).
  {
    short8 ah0[2], ah1[2];
    #pragma unroll
    for (int ks = 0; ks < 2; ++ks)
      ah0[ks] = *(const short8*)((const char*)h2t + (nidx*72 + ks*32 + quad*8)*2);
    if (two){
      #pragma unroll
      for (int ks = 0; ks < 2; ++ks)
        ah1[ks] = *(const short8*)((const char*)h2t + ((16+nidx)*72 + ks*32 + quad*8)*2);
    }
    // carrier: A[cl][63] = -1e8 (bf16) for padded rows cl >= V; w3 B[63][*] = log2e
    if (quad == 3){
      if (two) ah1[1][7] = (short)((16 + nidx >= V) ? f2bf(-1e8f) : (ushort_t)0);
      else     ah0[1][7] = (short)((nidx >= V)      ? f2bf(-1e8f) : (ushort_t)0);
    }
    const int t_out = wvi*16 + nidx;          // constant per lane
    const int rA = quad*4;
    float acc_t = 0.f;                        // running sum over i (quad 0 uses)
    if (two){
      #pragma unroll
      for (int it = 0; it < 17; ++it){
        short8 bh0 = w3bhi[((wvi + it*4)*2+0)*64 + lane];
        short8 bh1 = w3bhi[((wvi + it*4)*2+1)*64 + lane];
        floatx4 a0 = {0.f,0.f,0.f,0.f}, a1 = {0.f,0.f,0.f,0.f};
        a0 = MFMA16(ah0[0], bh0, a0); a0 = MFMA16(ah0[1], bh1, a0);
        a1 = MFMA16(ah1[0], bh0, a1); a1 = MFMA16(ah1[1], bh1, a1);

        const float4 xA = *(const float4*)(xst + it*36 + rA);
        const float4 xB = *(const float4*)(xst + it*36 + rA + 16);
        float den0 = 0.f, den1 = 0.f, num0 = 0.f, num1 = 0.f;
        float e;
        e = fast_exp2(a0[0]); den0 += e; num0 = fmaf(e, xA.x, num0);
        e = fast_exp2(a0[1]); den0 += e; num0 = fmaf(e, xA.y, num0);
        e = fast_exp2(a0[2]); den0 += e; num0 = fmaf(e, xA.z, num0);
        e = fast_exp2(a0[3]); den0 += e; num0 = fmaf(e, xA.w, num0);
        e = fast_exp2(a1[0]); den1 += e; num1 = fmaf(e, xB.x, num1);
        e = fast_exp2(a1[1]); den1 += e; num1 = fmaf(e, xB.y, num1);
        e = fast_exp2(a1[2]); den1 += e; num1 = fmaf(e, xB.z, num1);
        e = fast_exp2(a1[3]); den1 += e; num1 = fmaf(e, xB.w, num1);
        float den = den0 + den1, num = num0 + num1;
        den += __shfl_xor(den, 16, 64); den += __shfl_xor(den, 32, 64);
        num += __shfl_xor(num, 16, 64); num += __shfl_xor(num, 32, 64);
        float res = (den > 0.f) ? num * fast_rcp(den) : xsumv[it] * (1.f/32.f);
        acc_t += res;
      }
    } else {
      #pragma unroll
      for (int it = 0; it < 17; ++it){
        short8 bh0 = w3bhi[((wvi + it*4)*2+0)*64 + lane];
        short8 bh1 = w3bhi[((wvi + it*4)*2+1)*64 + lane];
        floatx4 a0 = {0.f,0.f,0.f,0.f};
        a0 = MFMA16(ah0[0], bh0, a0); a0 = MFMA16(ah0[1], bh1, a0);

        const float4 xA = *(const float4*)(xst + it*36 + rA);
        float den = 0.f, num = 0.f, e;
        e = fast_exp2(a0[0]); den += e; num = fmaf(e, xA.x, num);
        e = fast_exp2(a0[1]); den += e; num = fmaf(e, xA.y, num);
        e = fast_exp2(a0[2]); den += e; num = fmaf(e, xA.z, num);
        e = fast_exp2(a0[3]); den += e; num = fmaf(e, xA.w, num);
        den += __shfl_xor(den, 16, 64); den += __shfl_xor(den, 32, 64);
        num += __shfl_xor(num, 16, 64); num += __shfl_xor(num, 32, 64);
        float res = (den > 0.f) ? num * fast_rcp(den) : xsumv[it] * (1.f/32.f);
        acc_t += res;
      }
    }
    if (quad == 0 && t_out < TT_)
      xp[p*D_ + t_out] = fmaxf(acc_t + tb[t_out], 0.f);
  }
  if (tid == 0){
    float mp = (V > 0) ? 1.f : 0.f;
    xp[p*D_ + TT_] = mp;
    pm[p] = mp;
  }
}

// -------------------------------------------------------------------------
// BOTH transformer layers fused, one block per bn — 512 threads (8 waves).
// R3: in-wave LayerNorm; fused FF-reduce + LN2 epilogue.
// R8: the l==1 epilogue atomically accumulates the mean-over-N directly into
// xsws (replaces the xout write + mean_kernel; xsws pre-zeroed by ttcn).
// -------------------------------------------------------------------------
__global__ __launch_bounds__(512) void layer12_kernel(
    const float* __restrict__ xin, const float* __restrict__ pm,
    const short8* __restrict__ frS,
    const float* __restrict__ gqb, const float* __restrict__ gkb,
    const float* __restrict__ gvb, const float* __restrict__ gob,
    const float* __restrict__ inb, const float* __restrict__ outb,
    const float* __restrict__ ln1g, const float* __restrict__ ln1b,
    const float* __restrict__ fb1, const float* __restrict__ fb2,
    const float* __restrict__ ln2g, const float* __restrict__ ln2b,
    float* __restrict__ xsws)
{
  __shared__ __align__(16) float xb[16*68];
  __shared__ __align__(16) float xb2[16*68];
  __shared__ __align__(16) float q_[16*68];
  __shared__ __align__(16) float k_[16*68];
  __shared__ __align__(16) float v_[16*68];
  __shared__ __align__(16) float ao[16*68];
  __shared__ __align__(16) float ss[1024];
  __shared__ __align__(16) short8 fragA[256];
  __shared__ __align__(16) float hbuf[8*16*36];
  __shared__ __align__(16) float part[8*16*68];
  __shared__ __align__(16) float pe_t[1024];
  __shared__ float tbt[16];
  __shared__ float pmv[16];

  const int bn = blockIdx.x, tid = threadIdx.x;
  const int lane = tid & 63, wvi = tid >> 6;        // wvi 0..7
  const int nidx = lane & 15, quad = lane >> 4;
  const float* xin_p = xin + bn*1024;

  for (int o = tid; o < 1024; o += 512) xb[(o>>6)*68 + (o&63)] = xin_p[o];
  if (tid < 16) pmv[tid] = pm[bn*16 + tid];
  for (int o = tid; o < 1024; o += 512){
    int tok = o >> 6, d = o & 63;
    float div = __expf((float)(d & ~1) * (-0.14391156831212793f)); // -ln(1e4)/64
    float arg = (float)tok * div;
    pe_t[o] = (d & 1) ? cosf(arg) : sinf(arg);
  }
  if (tid >= 32 && tid < 48) tbt[tid-32] = logf(expf(-5.0f*(float)(tid-32)) + 1e-12f);
  __syncthreads();

  for (int l = 0; l < 2; ++l){
    const int lbase = 9472 + l*36864;
    const float* gqbL = gqb + l*64;  const float* gkbL = gkb + l*64;
    const float* gvbL = gvb + l*64;  const float* gobL = gob + l*64;
    const float* inbL = inb + l*192; const float* outbL = outb + l*64;
    const float* ln1gL = ln1g + l*64; const float* ln1bL = ln1b + l*64;
    const float* fb1L = fb1 + l*2048; const float* fb2L = fb2 + l*64;
    const float* ln2gL = ln2g + l*64; const float* ln2bL = ln2b + l*64;

    // save layer input for the l==1 residual (rows wvi and wvi+8, d=lane)
    float xres[2];
    xres[0] = xb[wvi*68 + lane];
    xres[1] = xb[(wvi+8)*68 + lane];

    // ===== PREFETCH WAVE 1: gattn units u0=wvi,u1=wvi+8; MHA units same;
    //       gattn-out (waves 0-3). Unit u lives at base + u*128 (q/k/v packed).
    short8 gU0[4], gU1[4], mU0[4], mU1[4], ob4[4];
    {
      int b0 = lbase + wvi*128;
      gU0[0] = frS[b0 + lane];       gU0[1] = frS[FRAG_TOT + b0 + lane];
      gU0[2] = frS[b0 + 64 + lane];  gU0[3] = frS[FRAG_TOT + b0 + 64 + lane];
      int m0 = lbase + OFF_INW + wvi*128;
      mU0[0] = frS[m0 + lane];       mU0[1] = frS[FRAG_TOT + m0 + lane];
      mU0[2] = frS[m0 + 64 + lane];  mU0[3] = frS[FRAG_TOT + m0 + 64 + lane];
      if (wvi < 4){
        int b1 = lbase + (wvi+8)*128;
        gU1[0] = frS[b1 + lane];       gU1[1] = frS[FRAG_TOT + b1 + lane];
        gU1[2] = frS[b1 + 64 + lane];  gU1[3] = frS[FRAG_TOT + b1 + 64 + lane];
        int m1 = lbase + OFF_INW + (wvi+8)*128;
        mU1[0] = frS[m1 + lane];       mU1[1] = frS[FRAG_TOT + m1 + lane];
        mU1[2] = frS[m1 + 64 + lane];  mU1[3] = frS[FRAG_TOT + m1 + 64 + lane];
        int bo = lbase + 1536 + wvi*128;   // gow
        ob4[0] = frS[bo + lane];       ob4[1] = frS[FRAG_TOT + bo + lane];
        ob4[2] = frS[bo + 64 + lane];  ob4[3] = frS[FRAG_TOT + bo + 64 + lane];
      }
    }

    // ---- gattn QKV (12 tiles over 8 waves) ----
    packA68(xb, fragA, tid);
    __syncthreads();
    {
      short8 axh0 = fragA[lane], axh1 = fragA[64+lane];
      short8 axl0 = fragA[128+lane], axl1 = fragA[192+lane];
      {
        int u = wvi;                           // u 0..7: q (0-3), k (4-7)
        floatx4 c = {0.f,0.f,0.f,0.f};
        c = mm3(axh0, axl0, gU0[0], gU0[1], c);
        c = mm3(axh1, axl1, gU0[2], gU0[3], c);
        int sel = u >> 2, d = (u & 3)*16 + nidx;
        float bb = (sel == 0 ? gqbL : gkbL)[d];
        float* dst = (sel == 0 ? q_ : k_);
        #pragma unroll
        for (int r = 0; r < 4; ++r) dst[(quad*4+r)*68 + d] = c[r] + bb;
      }
      if (wvi < 4){
        int u = wvi + 8;                       // u 8..11: v
        floatx4 c = {0.f,0.f,0.f,0.f};
        c = mm3(axh0, axl0, gU1[0], gU1[1], c);
        c = mm3(axh1, axl1, gU1[2], gU1[3], c);
        int d = (u & 3)*16 + nidx;
        float bb = gvbL[d];
        #pragma unroll
        for (int r = 0; r < 4; ++r) v_[(quad*4+r)*68 + d] = c[r] + bb;
      }
    }
    __syncthreads();
    // ---- merged scores+softmax (64 rows x 8 lanes, all 512 threads) ----
    {
      int row = tid >> 3;                 // h*16+qm
      int h = row >> 4, qm = row & 15;
      int km0 = (tid & 7) * 2;
      float s2[2];
      #pragma unroll
      for (int j = 0; j < 2; ++j){
        int km = km0 + j;
        float acc = dot16(q_ + qm*68 + h*16, k_ + km*68 + h*16);
        int dd = qm - km; if (dd < 0) dd = -dd;
        acc = acc * 0.25f + tbt[dd];
        if (pmv[km] == 0.f) acc = -1e9f;
        s2[j] = acc;
      }
      float mx = fmaxf(s2[0], s2[1]);
      mx = fmaxf(mx, __shfl_xor(mx, 1, 64));
      mx = fmaxf(mx, __shfl_xor(mx, 2, 64));
      mx = fmaxf(mx, __shfl_xor(mx, 4, 64));
      float e2[2], se = 0.f;
      #pragma unroll
      for (int j = 0; j < 2; ++j){ e2[j] = __expf(s2[j]-mx); se += e2[j]; }
      se += __shfl_xor(se, 1, 64);
      se += __shfl_xor(se, 2, 64);
      se += __shfl_xor(se, 4, 64);
      float inv = fast_rcp(se);
      #pragma unroll
      for (int j = 0; j < 2; ++j) ss[row*16 + km0 + j] = e2[j]*inv;
    }
    __syncthreads();
    for (int o = tid; o < 1024; o += 512){
      int m = o >> 6, d = o & 63, h = d >> 4;
      float acc = 0.f;
      #pragma unroll
      for (int km = 0; km < 16; ++km) acc += ss[h*256 + m*16 + km] * v_[km*68 + d];
      ao[m*68 + d] = acc;
    }
    __syncthreads();
    packA68(ao, fragA, tid);
    __syncthreads();
    if (wvi < 4){
      short8 axh0 = fragA[lane], axh1 = fragA[64+lane];
      short8 axl0 = fragA[128+lane], axl1 = fragA[192+lane];
      floatx4 c = {0.f,0.f,0.f,0.f};
      c = mm3(axh0, axl0, ob4[0], ob4[1], c);
      c = mm3(axh1, axl1, ob4[2], ob4[3], c);
      int d = wvi*16 + nidx;
      float bb = gobL[d];
      #pragma unroll
      for (int r = 0; r < 4; ++r){
        int tok = quad*4 + r;
        xb[tok*68 + d] += (c[r] + bb) * pmv[tok] + pe_t[tok*64 + d];
      }
    }
    __syncthreads();

    // ===== PREFETCH WAVE 2: MHA-out (waves 0-3) + FF f1/f2 initial (8 waves)
    short8 mob[4], f1c[4], f2c[4];
    if (wvi < 4){
      int base = lbase + OFF_OUTW + wvi*128;
      mob[0] = frS[base + lane];       mob[1] = frS[FRAG_TOT + base + lane];
      mob[2] = frS[base + 64 + lane];  mob[3] = frS[FRAG_TOT + base + 64 + lane];
    }
    {
      int f1base = lbase + OFF_FW1, f2base = lbase + OFF_FW2;
      #pragma unroll
      for (int t2 = 0; t2 < 2; ++t2){
        int sb = f1base + ((wvi*16+t2)*2)*64 + lane;
        f1c[t2*2+0] = frS[sb];
        f1c[t2*2+1] = frS[sb + 64];
      }
      #pragma unroll
      for (int ntd = 0; ntd < 4; ++ntd)
        f2c[ntd] = frS[f2base + (ntd*64 + wvi*8)*64 + lane];
    }

    // ---- MHA QKV (12 tiles over 8 waves) ----
    packA68(xb, fragA, tid);
    __syncthreads();
    {
      short8 axh0 = fragA[lane], axh1 = fragA[64+lane];
      short8 axl0 = fragA[128+lane], axl1 = fragA[192+lane];
      {
        int u = wvi;
        floatx4 c = {0.f,0.f,0.f,0.f};
        c = mm3(axh0, axl0, mU0[0], mU0[1], c);
        c = mm3(axh1, axl1, mU0[2], mU0[3], c);
        int sel = u >> 2, d = (u & 3)*16 + nidx;
        float bb = inbL[u*16 + nidx];
        float* dst = (sel == 0 ? q_ : k_);
        #pragma unroll
        for (int r = 0; r < 4; ++r) dst[(quad*4+r)*68 + d] = c[r] + bb;
      }
      if (wvi < 4){
        int u = wvi + 8;
        floatx4 c = {0.f,0.f,0.f,0.f};
        c = mm3(axh0, axl0, mU1[0], mU1[1], c);
        c = mm3(axh1, axl1, mU1[2], mU1[3], c);
        int d = (u & 3)*16 + nidx;
        float bb = inbL[u*16 + nidx];
        #pragma unroll
        for (int r = 0; r < 4; ++r) v_[(quad*4+r)*68 + d] = c[r] + bb;
      }
    }
    __syncthreads();
    {
      int row = tid >> 3;
      int h = row >> 4, qm = row & 15;
      int km0 = (tid & 7) * 2;
      float s2[2];
      #pragma unroll
      for (int j = 0; j < 2; ++j)
        s2[j] = 0.25f * dot16(q_ + qm*68 + h*16, k_ + (km0+j)*68 + h*16);
      float mx = fmaxf(s2[0], s2[1]);
      mx = fmaxf(mx, __shfl_xor(mx, 1, 64));
      mx = fmaxf(mx, __shfl_xor(mx, 2, 64));
      mx = fmaxf(mx, __shfl_xor(mx, 4, 64));
      float e2[2], se = 0.f;
      #pragma unroll
      for (int j = 0; j < 2; ++j){ e2[j] = __expf(s2[j]-mx); se += e2[j]; }
      se += __shfl_xor(se, 1, 64);
      se += __shfl_xor(se, 2, 64);
      se += __shfl_xor(se, 4, 64);
      float inv = fast_rcp(se);
      #pragma unroll
      for (int j = 0; j < 2; ++j) ss[row*16 + km0 + j] = e2[j]*inv;
    }
    __syncthreads();
    for (int o = tid; o < 1024; o += 512){
      int m = o >> 6, d = o & 63, h = d >> 4;
      float acc = 0.f;
      #pragma unroll
      for (int km = 0; km < 16; ++km) acc += ss[h*256 + m*16 + km] * v_[km*68 + d];
      ao[m*68 + d] = acc;
    }
    __syncthreads();
    packA68(ao, fragA, tid);
    __syncthreads();
    if (wvi < 4){
      short8 axh0 = fragA[lane], axh1 = fragA[64+lane];
      short8 axl0 = fragA[128+lane], axl1 = fragA[192+lane];
      floatx4 c = {0.f,0.f,0.f,0.f};
      c = mm3(axh0, axl0, mob[0], mob[1], c);
      c = mm3(axh1, axl1, mob[2], mob[3], c);
      int d = wvi*16 + nidx;
      float bb = outbL[d];
      #pragma unroll
      for (int r = 0; r < 4; ++r) xb[(quad*4+r)*68 + d] += c[r] + bb;
    }
    __syncthreads();

    // ---- LN1: in-wave (wave w -> tokens w, w+8; lane = d) -> xb2 ----
    {
      float a = xb[wvi*68 + lane], b = xb[(wvi+8)*68 + lane];
      float mua = wsum64(a) * (1.f/64.f);
      float mub = wsum64(b) * (1.f/64.f);
      float da = a - mua, db = b - mub;
      float va = wsum64(da*da) * (1.f/64.f);
      float vb = wsum64(db*db) * (1.f/64.f);
      float rva = rsqrtf(va + 1e-5f), rvb = rsqrtf(vb + 1e-5f);
      float g = ln1gL[lane], bia = ln1bL[lane];
      xb2[wvi*68 + lane]     = da*rva*g + bia;
      xb2[(wvi+8)*68 + lane] = db*rvb*g + bia;
    }
    __syncthreads();
    packA68(xb2, fragA, tid);
    __syncthreads();

    // ---- FF (2048 hidden over 8 waves, 8 iters each); f1/f2 prefetch 1 ahead
    {
      const int w = wvi;
      const int f1base = lbase + OFF_FW1, f2base = lbase + OFF_FW2;
      short8 axh0 = fragA[lane], axh1 = fragA[64 + lane];
      floatx4 y0 = {0.f,0.f,0.f,0.f}, y1 = y0, y2 = y0, y3 = y0;
      float* hw = hbuf + w*576;

      short8 f1n[4], f2n[4];
      for (int it = 0; it < 8; ++it){
        int ntA = w*16 + it*2;
        floatx4 hA = {0.f,0.f,0.f,0.f}, hB = hA;
        hA = MFMA16(axh0, f1c[0], hA); hA = MFMA16(axh1, f1c[1], hA);
        hB = MFMA16(axh0, f1c[2], hB); hB = MFMA16(axh1, f1c[3], hB);
        float bbA = fb1L[ntA*16 + nidx], bbB = fb1L[ntA*16 + 16 + nidx];
        #pragma unroll
        for (int r = 0; r < 4; ++r){
          hw[(quad*4+r)*36 + nidx]      = fmaxf(hA[r] + bbA, 0.f);
          hw[(quad*4+r)*36 + 16 + nidx] = fmaxf(hB[r] + bbB, 0.f);
        }
        if (it < 7){
          int ntN = ntA + 2, kstN = w*8 + it + 1;
          #pragma unroll
          for (int t2 = 0; t2 < 2; ++t2){
            int sb = f1base + ((ntN+t2)*2)*64 + lane;
            f1n[t2*2+0] = frS[sb];
            f1n[t2*2+1] = frS[sb + 64];
          }
          #pragma unroll
          for (int ntd = 0; ntd < 4; ++ntd)
            f2n[ntd] = frS[f2base + (ntd*64 + kstN)*64 + lane];
        }
        short8 ah = cvt8s(hw + (lane & 15)*36 + quad*8);
        y0 = MFMA16(ah, f2c[0], y0);
        y1 = MFMA16(ah, f2c[1], y1);
        y2 = MFMA16(ah, f2c[2], y2);
        y3 = MFMA16(ah, f2c[3], y3);
        #pragma unroll
        for (int j = 0; j < 4; ++j){ f1c[j] = f1n[j]; f2c[j] = f2n[j]; }
      }
      #pragma unroll
      for (int r = 0; r < 4; ++r){
        int row = (quad*4 + r)*68;
        part[w*1088 + row + nidx]      = y0[r];
        part[w*1088 + row + 16 + nidx] = y1[r];
        part[w*1088 + row + 32 + nidx] = y2[r];
        part[w*1088 + row + 48 + nidx] = y3[r];
      }
    }
    __syncthreads();
    // ---- FF part-reduce + fb2 + LN2 + residual; l==1 -> atomic mean ----
    {
      float ra = xb2[wvi*68 + lane] + fb2L[lane];
      float rb = xb2[(wvi+8)*68 + lane] + fb2L[lane];
      #pragma unroll
      for (int ww = 0; ww < 8; ++ww){
        ra += part[ww*1088 + wvi*68 + lane];
        rb += part[ww*1088 + (wvi+8)*68 + lane];
      }
      float mua = wsum64(ra) * (1.f/64.f);
      float mub = wsum64(rb) * (1.f/64.f);
      float da = ra - mua, db = rb - mub;
      float va = wsum64(da*da) * (1.f/64.f);
      float vb = wsum64(db*db) * (1.f/64.f);
      float rva = rsqrtf(va + 1e-5f), rvb = rsqrtf(vb + 1e-5f);
      float g = ln2gL[lane], bia = ln2bL[lane];
      float vva = da*rva*g + bia;
      float vvb = db*rvb*g + bia;
      if (l == 0){
        xb[wvi*68 + lane]     = vva;               // becomes layer-1 input
        xb[(wvi+8)*68 + lane] = vvb;
      } else {
        int b = bn >> 5;                            // N_ = 32
        atomicAdd(&xsws[(b*M_ + wvi)*64 + lane],     (vva + xres[0]) * (1.f/32.f));
        atomicAdd(&xsws[(b*M_ + wvi + 8)*64 + lane], (vvb + xres[1]) * (1.f/32.f));
      }
    }
    __syncthreads();
  }
}

// -------------------------------------------------------------------------
// Classifier head. One block per b. (small; fp32). xs = mean over N,
// accumulated atomically by layer12 (R8).
// -------------------------------------------------------------------------
__global__ __launch_bounds__(256) void final_kernel(
    const float* __restrict__ xsws, const float* __restrict__ pm,
    const float* __restrict__ q_embed,
    const float* __restrict__ cin_w, const float* __restrict__ cin_b,
    const float* __restrict__ cout_w, const float* __restrict__ cout_b,
    const float* __restrict__ logit_w, const float* __restrict__ logit_b,
    float* __restrict__ out)
{
  const int b = blockIdx.x;
  const int tid = threadIdx.x;
  __shared__ __align__(16) float xs[M_ * D_];
  __shared__ float kpmv[M_];
  __shared__ __align__(16) float qv[5 * D_], kv[M_ * D_], vv[M_ * D_];
  __shared__ float sv[H_ * 5 * M_];
  __shared__ __align__(16) float ao[5 * D_], zv[5 * D_];

  for (int o = tid; o < M_ * D_; o += 256) xs[o] = xsws[b*M_*D_ + o];
  if (tid < M_) {
    float any = 0.f;
    #pragma unroll
    for (int n = 0; n < N_; ++n) any += (pm[(b * N_ + n) * M_ + tid] > 0.f) ? 1.f : 0.f;
    kpmv[tid] = (any > 0.f) ? 0.f : 1.f;
  }
  __syncthreads();

  for (int o = tid; o < 5 * D_; o += 256) {
    int qi = o >> 6, d = o & 63;
    qv[o] = cin_b[d] + dot64(q_embed + qi * D_, cin_w + d * D_);
  }
  for (int o = tid; o < 2 * M_ * D_; o += 256) {
    int sel = o >> 10, r = o & 1023, m = r >> 6, d = r & 63;
    float acc = cin_b[D_ + sel * D_ + d] + dot64(xs + m * D_, cin_w + (D_ + sel * D_ + d) * D_);
    ((sel == 0) ? kv : vv)[r] = acc;
  }
  __syncthreads();

  for (int o = tid; o < H_ * 5 * M_; o += 256) {
    int h = o / 80, r = o % 80, qi = r >> 4, km = r & 15;
    float acc = 0.25f * dot16(qv + qi * D_ + h * DH_, kv + km * D_ + h * DH_);
    if (kpmv[km] != 0.f) acc = -1e9f;
    sv[o] = acc;
  }
  __syncthreads();
  if (tid < H_ * 5) {
    int h = tid / 5, qi = tid % 5;
    float* row = sv + h * 80 + qi * M_;
    float mx = -1e30f;
    #pragma unroll
    for (int km = 0; km < M_; ++km) mx = fmaxf(mx, row[km]);
    float se = 0.f;
    #pragma unroll
    for (int km = 0; km < M_; ++km) { float e = __expf(row[km] - mx); row[km] = e; se += e; }
    float inv = 1.f / se;
    #pragma unroll
    for (int km = 0; km < M_; ++km) row[km] *= inv;
  }
  __syncthreads();
  for (int o = tid; o < 5 * D_; o += 256) {
    int qi = o >> 6, d = o & 63, h = d >> 4;
    float acc = 0.f;
    #pragma unroll
    for (int km = 0; km < M_; ++km) acc += sv[h * 80 + qi * M_ + km] * vv[km * D_ + d];
    ao[o] = acc;
  }
  __syncthreads();
  for (int o = tid; o < 5 * D_; o += 256) {
    int qi = o >> 6, d = o & 63;
    zv[o] = cout_b[d] + dot64(ao + qi * D_, cout_w + d * D_);
  }
  __syncthreads();
  if (tid < 5) {
    float acc = logit_b[0] + dot64(zv + tid * D_, logit_w);
    out[b * 5 + tid] = acc;
  }
}

// -------------------------------------------------------------------------
extern "C" void kernel_launch(void* const* d_in, const int* in_sizes, int n_in,
                              void* d_out, int out_size, void* d_ws, size_t ws_size,
                              hipStream_t stream) {
  const float* x       = (const float*)d_in[0];
  const int*   mask    = (const int*)  d_in[1];
  const float* ttcn_w1 = (const float*)d_in[2];
  const float* ttcn_b1 = (const float*)d_in[3];
  const float* ttcn_w2 = (const float*)d_in[4];
  const float* ttcn_b2 = (const float*)d_in[5];
  const float* ttcn_w3 = (const float*)d_in[6];
  const float* ttcn_b3 = (const float*)d_in[7];   // unused: cancels in softmax
  const float* t_bias  = (const float*)d_in[8];
  const float* ga_qw   = (const float*)d_in[9];
  const float* ga_qb   = (const float*)d_in[10];
  const float* ga_kw   = (const float*)d_in[11];
  const float* ga_kb   = (const float*)d_in[12];
  const float* ga_vw   = (const float*)d_in[13];
  const float* ga_vb   = (const float*)d_in[14];
  const float* ga_ow   = (const float*)d_in[15];
  const float* ga_ob   = (const float*)d_in[16];
  const float* tf_in_w = (const float*)d_in[17];
  const float* tf_in_b = (const float*)d_in[18];
  const float* tf_out_w= (const float*)d_in[19];
  const float* tf_out_b= (const float*)d_in[20];
  const float* tf_ln1g = (const float*)d_in[21];
  const float* tf_ln1b = (const float*)d_in[22];
  const float* tf_ln2g = (const float*)d_in[23];
  const float* tf_ln2b = (const float*)d_in[24];
  const float* tf_fw1  = (const float*)d_in[25];
  const float* tf_fb1  = (const float*)d_in[26];
  const float* tf_fw2  = (const float*)d_in[27];
  const float* tf_fb2  = (const float*)d_in[28];
  const float* q_embed = (const float*)d_in[29];
  const float* cls_in_w  = (const float*)d_in[30];
  const float* cls_in_b  = (const float*)d_in[31];
  const float* cls_out_w = (const float*)d_in[32];
  const float* cls_out_b = (const float*)d_in[33];
  const float* logit_w = (const float*)d_in[34];
  const float* logit_b = (const float*)d_in[35];
  (void)ttcn_b3;

  float* wsf  = (float*)d_ws;
  float* xp   = wsf;                        // 262144 f
  float* pmb  = wsf + P_TOT * D_;           // 4096 f
  uint4* fr   = (uint4*)(pmb + P_TOT);      // 2*FRAG_TOT uint4
  float* xsws = (float*)(fr + 2*FRAG_TOT);  // 8192 f (atomic mean over N)
  const short8* frS = (const short8*)fr;

  prep_kernel<<<325, 256, 0, stream>>>(ttcn_w1, ttcn_w2, ttcn_w3,
      ga_qw, ga_kw, ga_vw, ga_ow, tf_in_w, tf_out_w, tf_fw1, tf_fw2, fr);

  ttcn_kernel<<<P_TOT, 256, 0, stream>>>(x, mask, ttcn_b1, ttcn_b2, t_bias,
      frS + 0, frS + 256, frS + 768,
      xp, pmb, xsws);

  layer12_kernel<<<BN_, 512, 0, stream>>>(xp, pmb, frS,
      ga_qb, ga_kb, ga_vb, ga_ob, tf_in_b, tf_out_b, tf_ln1g, tf_ln1b,
      tf_fb1, tf_fb2, tf_ln2g, tf_ln2b, xsws);

  final_kernel<<<B_, 256, 0, stream>>>(xsws, pmb, q_embed,
                                       cls_in_w, cls_in_b, cls_out_w, cls_out_b,
                                       logit_w, logit_b, (float*)d_out);
}